// Round 7
// baseline (3275.193 us; speedup 1.0000x reference)
//
#include <hip/hip_runtime.h>
#include <hip/hip_fp16.h>
#include <stdint.h>

#define B_ 64
#define T_ 2048
#define I_ 16
#define H_ 256
#define G_ 768   // 3*H

typedef _Float16 f16;
typedef _Float16 half2_t __attribute__((ext_vector_type(2)));
typedef uint32_t u32x4 __attribute__((ext_vector_type(4)));

// ---------- fast math helpers ----------
__device__ __forceinline__ float fast_rcp(float x) {
#if __has_builtin(__builtin_amdgcn_rcpf)
    return __builtin_amdgcn_rcpf(x);
#else
    return 1.0f / x;
#endif
}
__device__ __forceinline__ float sigmoid_f(float x) {
    return fast_rcp(1.0f + __expf(-x));
}
__device__ __forceinline__ float tanh_f(float x) {
    float e = __expf(2.0f * x);
    return 1.0f - 2.0f * fast_rcp(e + 1.0f);
}

__device__ __forceinline__ float fdot2(uint32_t a, uint32_t b, float c) {
#if __has_builtin(__builtin_amdgcn_fdot2)
    return __builtin_amdgcn_fdot2(__builtin_bit_cast(half2_t, a),
                                  __builtin_bit_cast(half2_t, b), c, false);
#else
    half2_t ha = __builtin_bit_cast(half2_t, a), hb = __builtin_bit_cast(half2_t, b);
    return c + (float)ha.x * (float)hb.x + (float)ha.y * (float)hb.y;
#endif
}
__device__ __forceinline__ float dot_u4(u32x4 w, u32x4 h, float acc) {
    acc = fdot2(w.x, h.x, acc);
    acc = fdot2(w.y, h.y, acc);
    acc = fdot2(w.z, h.z, acc);
    acc = fdot2(w.w, h.w, acc);
    return acc;
}

// asm-def weight load: the def is an INLINEASM — RA can neither rematerialize it
// nor re-load it. With waves_per_eu(2,2) the VGPR budget is 256, so RA keeps
// these in registers instead of spilling them to scratch.
__device__ __forceinline__ u32x4 wload(const u32x4* p) {
    u32x4 r;
    asm volatile("global_load_dwordx4 %0, %1, off" : "=v"(r) : "v"(p));
    return r;
}

// ---------- weight fp32 -> packed fp16 conversion ----------
// dword layout: [0,98304) Whh0 row-major | [98304,196608) Whh1 row-major |
//               [196608,294912) Wih1T k-major | [294912,327680) W1T k-major
__global__ __launch_bounds__(256) void cvt_weights(const float* __restrict__ whh0,
                                                   const float* __restrict__ whh1,
                                                   const float* __restrict__ wih1,
                                                   const float* __restrict__ w1,
                                                   uint32_t* __restrict__ out) {
    int idx = blockIdx.x * 256 + threadIdx.x;
    if (idx >= 327680) return;
    const float* s;
    if (idx < 196608) {
        const float* w = (idx < 98304) ? whh0 : whh1;
        int local = (idx < 98304) ? idx : idx - 98304;
        int row = local >> 7, kd = local & 127;
        s = w + (size_t)row * 256 + kd * 2;
    } else if (idx < 294912) {
        int local = idx - 196608;
        int u4 = local >> 2, d = local & 3;
        int k8 = u4 / 768, g = u4 - k8 * 768;
        s = wih1 + (size_t)g * 256 + k8 * 8 + d * 2;
    } else {
        int local = idx - 294912;
        int u4 = local >> 2, d = local & 3;
        int k8 = u4 >> 8, g = u4 & 255;
        s = w1 + (size_t)g * 256 + k8 * 8 + d * 2;
    }
    half2_t h;
    h.x = (f16)s[0];
    h.y = (f16)s[1];
    out[idx] = __builtin_bit_cast(uint32_t, h);
}

// =======================================================================
// role bodies
// =======================================================================

// ---------- xg0: 512 threads, one 64-row tile ----------
__device__ __forceinline__ void xg0_body(const float* __restrict__ x,
        const float* __restrict__ wih0, const float* __restrict__ bih0,
        float* __restrict__ xg, int t0, int C, int blk, char* smem) {
    float (*xs)[16] = (float(*)[16])smem;
    int tid = threadIdx.x;
    int m0 = blk * 64;
    if (tid < 256) {
        int r = tid >> 2, c4 = (tid & 3) * 4;
        int m = m0 + r;
        int b = m / C, tl = m - b * C;
        float4 v = *(const float4*)(x + (size_t)(b * T_ + t0 + tl) * I_ + c4);
        *(float4*)&xs[r][c4] = v;
    }
    __syncthreads();
    for (int g = tid; g < G_; g += 512) {
        const float4* wr = (const float4*)(wih0 + (size_t)g * I_);
        float4 w0 = wr[0], w1 = wr[1], w2 = wr[2], w3 = wr[3];
        float bias = bih0[g];
        float* outp = xg + (size_t)m0 * G_ + g;
        for (int m = 0; m < 64; ++m) {
            const float4* xr4 = (const float4*)xs[m];
            float4 a0 = xr4[0], a1 = xr4[1], a2 = xr4[2], a3 = xr4[3];
            float acc = bias;
            acc += a0.x*w0.x + a0.y*w0.y + a0.z*w0.z + a0.w*w0.w;
            acc += a1.x*w1.x + a1.y*w1.y + a1.z*w1.z + a1.w*w1.w;
            acc += a2.x*w2.x + a2.y*w2.y + a2.z*w2.z + a2.w*w2.w;
            acc += a3.x*w3.x + a3.y*w3.y + a3.z*w3.z + a3.w*w3.w;
            outp[(size_t)m * G_] = acc;
        }
    }
}

// ---------- regressor: 512 threads, one 64-row tile, 8g x 4m register tile ----------
__device__ __forceinline__ void reg_body(const f16* __restrict__ h2,
        const uint32_t* __restrict__ w1T, const float* __restrict__ b1,
        const float* __restrict__ w2, const float* __restrict__ b2,
        float* __restrict__ out, int t0, int C, int lgC, int blk, char* smem) {
    u32x4 (*hs)[32] = (u32x4(*)[32])smem;            // 32 KB
    float (*red)[4] = (float(*)[4])(smem + 32768);   // [16][4]
    int tid = threadIdx.x;
    int m0 = blk * 64;
    const u32x4* hsrc = (const u32x4*)h2 + (size_t)m0 * 32;
    #pragma unroll
    for (int it = 0; it < 4; ++it) {
        int o = tid + it * 512;
        hs[o >> 5][o & 31] = hsrc[o];
    }
    __syncthreads();
    int gg = tid & 31, mg = tid >> 5;
    const u32x4* wt = (const u32x4*)w1T;
    float acc[8][4];
    #pragma unroll
    for (int i = 0; i < 8; ++i)
        #pragma unroll
        for (int r = 0; r < 4; ++r) acc[i][r] = 0.0f;
    for (int k8 = 0; k8 < 32; ++k8) {
        u32x4 w[8], h[4];
        #pragma unroll
        for (int i = 0; i < 8; ++i) w[i] = wt[(size_t)k8 * 256 + gg + 32 * i];
        #pragma unroll
        for (int r = 0; r < 4; ++r) h[r] = hs[mg * 4 + r][k8];
        #pragma unroll
        for (int i = 0; i < 8; ++i)
            #pragma unroll
            for (int r = 0; r < 4; ++r)
                acc[i][r] = dot_u4(w[i], h[r], acc[i][r]);
    }
    float pv[4] = {0, 0, 0, 0};
    #pragma unroll
    for (int i = 0; i < 8; ++i) {
        int g = gg + 32 * i;
        float bias = b1[g], w2g = w2[g];
        #pragma unroll
        for (int r = 0; r < 4; ++r)
            pv[r] += w2g * fmaxf(acc[i][r] + bias, 0.0f);
    }
    #pragma unroll
    for (int r = 0; r < 4; ++r) {
        pv[r] += __shfl_xor(pv[r], 1, 64);
        pv[r] += __shfl_xor(pv[r], 2, 64);
        pv[r] += __shfl_xor(pv[r], 4, 64);
        pv[r] += __shfl_xor(pv[r], 8, 64);
        pv[r] += __shfl_xor(pv[r], 16, 64);
    }
    if (gg == 0) {
        #pragma unroll
        for (int r = 0; r < 4; ++r) red[mg][r] = pv[r];
    }
    __syncthreads();
    if (tid < 64) {
        int m = m0 + tid;
        float v = fmaxf(red[tid >> 2][tid & 3] + b2[0], 0.0f);
        int b = m >> lgC, tl = m & (C - 1);
        out[(size_t)b * T_ + t0 + tl] = v;
    }
}

// ---------- GRU recurrence, R=6/Q=4, weights resident via asm-def loads ----------
#define LOADROW(t, BASE) \
    u32x4 W##t##0 = wload(wu + (BASE) + 0), W##t##1 = wload(wu + (BASE) + 1), \
          W##t##2 = wload(wu + (BASE) + 2), W##t##3 = wload(wu + (BASE) + 3), \
          W##t##4 = wload(wu + (BASE) + 4), W##t##5 = wload(wu + (BASE) + 5), \
          W##t##6 = wload(wu + (BASE) + 6), W##t##7 = wload(wu + (BASE) + 7);

#define DOTU(u) { u32x4 hv = hp[u]; \
    a0 = dot_u4(W0##u, hv, a0); a1 = dot_u4(W1##u, hv, a1); \
    a2 = dot_u4(W2##u, hv, a2); a3 = dot_u4(W3##u, hv, a3); \
    a4 = dot_u4(W4##u, hv, a4); a5 = dot_u4(W5##u, hv, a5); }

__device__ __forceinline__ void rec_body(const uint32_t* __restrict__ whh,
        const float* __restrict__ bhh, const float* __restrict__ xg,
        f16* __restrict__ hout, float* __restrict__ state,
        int b, int C, char* smem) {
    uint32_t (*hq)[4][36] = (uint32_t(*)[4][36])smem; // padded quarters, broadcast-friendly

    int tid = threadIdx.x;
    int g = tid >> 2, q = tid & 3;

    const u32x4* wu = (const u32x4*)whh;
    // 6 rows x 8 u32x4 = 192 VGPRs of weights, defs are inline asm (unreloadable)
    LOADROW(0, (g)       * 32 + q * 8)
    LOADROW(1, (128 + g) * 32 + q * 8)
    LOADROW(2, (256 + g) * 32 + q * 8)
    LOADROW(3, (384 + g) * 32 + q * 8)
    LOADROW(4, (512 + g) * 32 + q * 8)
    LOADROW(5, (640 + g) * 32 + q * 8)
    // the asm loads are not compiler-tracked: drain them explicitly, then fence
    // the scheduler so no use is hoisted above the wait (guide rule #18)
    asm volatile("s_waitcnt vmcnt(0)" ::: "memory");
    __builtin_amdgcn_sched_barrier(0);

    int j = g + (q << 7); // valid for q<2
    float h_old = 0.0f, bhr = 0.0f, bhz = 0.0f, bhn = 0.0f;
    if (q < 2) {
        h_old = state[b * 256 + j];
        bhr = bhh[j]; bhz = bhh[256 + j]; bhn = bhh[512 + j];
        ((f16*)&hq[0][j >> 6][0])[j & 63] = (f16)h_old;
    }
    __syncthreads();

    const float* xgt = xg + (size_t)b * C * G_;
    f16* hob = hout + (size_t)b * C * H_;

    for (int tl = 0; tl < C; ++tl) {
        int p = tl & 1;
        float xr = 0, xz = 0, xn = 0;
        if (q < 2) { xr = xgt[j]; xz = xgt[256 + j]; xn = xgt[512 + j]; }

        const u32x4* hp = (const u32x4*)&hq[p][q][0];
        float a0 = 0, a1 = 0, a2 = 0, a3 = 0, a4 = 0, a5 = 0;
        DOTU(0) DOTU(1) DOTU(2) DOTU(3) DOTU(4) DOTU(5) DOTU(6) DOTU(7)

        a0 += __shfl_xor(a0, 1, 64); a0 += __shfl_xor(a0, 2, 64);
        a1 += __shfl_xor(a1, 1, 64); a1 += __shfl_xor(a1, 2, 64);
        a2 += __shfl_xor(a2, 1, 64); a2 += __shfl_xor(a2, 2, 64);
        a3 += __shfl_xor(a3, 1, 64); a3 += __shfl_xor(a3, 2, 64);
        a4 += __shfl_xor(a4, 1, 64); a4 += __shfl_xor(a4, 2, 64);
        a5 += __shfl_xor(a5, 1, 64); a5 += __shfl_xor(a5, 2, 64);

        if (q < 2) {
            float sumR = q ? a1 : a0;
            float sumZ = q ? a3 : a2;
            float sumN = q ? a5 : a4;
            float r = sigmoid_f(xr + sumR + bhr);
            float z = sigmoid_f(xz + sumZ + bhz);
            float n = tanh_f(xn + r * (sumN + bhn));
            h_old = z * (h_old - n) + n;   // (1-z)*n + z*h
            f16 hh = (f16)h_old;
            hob[(size_t)tl * H_ + j] = hh;
            ((f16*)&hq[p ^ 1][j >> 6][0])[j & 63] = hh;
        }
        __syncthreads();
        xgt += G_;
    }
    if (q < 2) state[b * 256 + j] = h_old;
}

// =======================================================================
// fused dispatch: blocks [0,64) rec0(i) | [64,128) rec1(i-1) |
//                 [128,128+C) xg0(i+1) | [128+C,128+2C) regressor(i-2)
// waves_per_eu(2,2): min=max=2 waves/EU -> VGPR budget 256, no occupancy
// incentive for RA to spill the 192 resident weight VGPRs.
// =======================================================================
__global__ __launch_bounds__(512)
__attribute__((amdgpu_waves_per_eu(2, 2)))
void fused_step(int i, int nC, int C, int lgC,
        const float* __restrict__ x,
        const float* __restrict__ wih0, const float* __restrict__ bih0,
        const uint32_t* __restrict__ whh0, const float* __restrict__ bhh0,
        const uint32_t* __restrict__ whh1, const float* __restrict__ bhh1,
        const uint32_t* __restrict__ w1T, const float* __restrict__ b1,
        const float* __restrict__ w2, const float* __restrict__ b2,
        float* __restrict__ xg0a, float* __restrict__ xg0b,
        float* __restrict__ xg1b,
        f16* __restrict__ h1,
        f16* __restrict__ h2a, f16* __restrict__ h2b,
        float* __restrict__ st0, float* __restrict__ st1,
        float* __restrict__ out) {
    __shared__ __align__(16) char smem[33024];
    int blk = blockIdx.x;
    if (blk < 128) {
        const uint32_t* whh; const float* bhh; const float* xgp; f16* hout; float* st; int b;
        if (blk < 64) {
            if (i >= nC) return;
            whh = whh0; bhh = bhh0; xgp = (i & 1) ? xg0b : xg0a;
            hout = h1; st = st0; b = blk;
        } else {
            if (i < 1) return;
            whh = whh1; bhh = bhh1; xgp = xg1b;
            hout = ((i - 1) & 1) ? h2b : h2a; st = st1; b = blk - 64;
        }
        rec_body(whh, bhh, xgp, hout, st, b, C, smem);
    } else if (blk < 128 + C) {
        if (i + 1 >= nC) return;
        xg0_body(x, wih0, bih0, ((i + 1) & 1) ? xg0b : xg0a, (i + 1) * C, C, blk - 128, smem);
    } else {
        if (i < 2) return;
        reg_body((i & 1) ? h2b : h2a, w1T, b1, w2, b2, out, (i - 2) * C, C, lgC,
                 blk - 128 - C, smem);
    }
}

// ---------- standalone wrappers ----------
__global__ __launch_bounds__(512, 2) void xg0_stand(const float* __restrict__ x,
        const float* __restrict__ wih0, const float* __restrict__ bih0,
        float* __restrict__ xg, int t0, int C) {
    __shared__ __align__(16) char smem[4096];
    xg0_body(x, wih0, bih0, xg, t0, C, blockIdx.x, smem);
}

__global__ __launch_bounds__(512, 2) void reg_stand(const f16* __restrict__ h2,
        const uint32_t* __restrict__ w1T, const float* __restrict__ b1,
        const float* __restrict__ w2, const float* __restrict__ b2,
        float* __restrict__ out, int t0, int C, int lgC) {
    __shared__ __align__(16) char smem[33024];
    reg_body(h2, w1T, b1, w2, b2, out, t0, C, lgC, blockIdx.x, smem);
}

// ---------- xg1 = bih1 + h1 @ Wih1^T  (standalone, on critical path) ----------
__global__ __launch_bounds__(256) void xg1_kernel(const f16* __restrict__ h1,
        const uint32_t* __restrict__ wih1T, const float* __restrict__ bih1,
        float* __restrict__ xg, int C) {
    __shared__ u32x4 hs[64][32]; // 32 KB
    int tid = threadIdx.x;
    int m0 = blockIdx.x * 64;
    int gbase = blockIdx.y * 256;
    const u32x4* hsrc = (const u32x4*)h1 + (size_t)m0 * 32;
    #pragma unroll
    for (int it = 0; it < 8; ++it) {
        int o = tid + it * 256;
        hs[o >> 5][o & 31] = hsrc[o];
    }
    __syncthreads();
    int gg = tid & 31, mg = tid >> 5;
    const u32x4* wt = (const u32x4*)wih1T;
    float acc[8][8];
    #pragma unroll
    for (int i = 0; i < 8; ++i)
        #pragma unroll
        for (int r = 0; r < 8; ++r) acc[i][r] = 0.0f;
    for (int k8 = 0; k8 < 32; ++k8) {
        u32x4 w[8], h[8];
        #pragma unroll
        for (int i = 0; i < 8; ++i) w[i] = wt[(size_t)k8 * 768 + gbase + gg + 32 * i];
        #pragma unroll
        for (int r = 0; r < 8; ++r) h[r] = hs[mg * 8 + r][k8];
        #pragma unroll
        for (int i = 0; i < 8; ++i)
            #pragma unroll
            for (int r = 0; r < 8; ++r)
                acc[i][r] = dot_u4(w[i], h[r], acc[i][r]);
    }
    #pragma unroll
    for (int i = 0; i < 8; ++i) {
        int g = gbase + gg + 32 * i;
        float bias = bih1[g];
        #pragma unroll
        for (int r = 0; r < 8; ++r)
            xg[(size_t)(m0 + mg * 8 + r) * G_ + g] = acc[i][r] + bias;
    }
}

// ---------- host ----------
extern "C" void kernel_launch(void* const* d_in, const int* in_sizes, int n_in,
                              void* d_out, int out_size, void* d_ws, size_t ws_size,
                              hipStream_t stream) {
    const float* x    = (const float*)d_in[0];
    const float* Wih0 = (const float*)d_in[1];
    const float* Whh0 = (const float*)d_in[2];
    const float* bih0 = (const float*)d_in[3];
    const float* bhh0 = (const float*)d_in[4];
    const float* Wih1 = (const float*)d_in[5];
    const float* Whh1 = (const float*)d_in[6];
    const float* bih1 = (const float*)d_in[7];
    const float* bhh1 = (const float*)d_in[8];
    const float* W1   = (const float*)d_in[9];
    const float* b1   = (const float*)d_in[10];
    const float* W2   = (const float*)d_in[11];
    const float* b2   = (const float*)d_in[12];
    float* out = (float*)d_out;

    char* ws = (char*)d_ws;
    uint32_t* wcvt = (uint32_t*)ws;             // 327680 dwords
    const uint32_t* whh0_16 = wcvt;
    const uint32_t* whh1_16 = wcvt + 98304;
    const uint32_t* wih1T   = wcvt + 196608;
    const uint32_t* w1T     = wcvt + 294912;
    float* state0 = (float*)(ws + 1310720);
    float* state1 = (float*)(ws + 1310720 + 65536);
    size_t fixed = 1310720 + 2 * 65536;

    // per-chunk: xg0 x2 + xg1 (196608C each) + h1 (32768C) + h2 x2 (32768C each)
    int C = 512;
    while (C > 32 && fixed + (size_t)C * 688128 > ws_size) C >>= 1;
    int lgC = 0; while ((1 << lgC) < C) lgC++;
    int nC = T_ / C;

    char* p = ws + fixed;
    float* xg0_buf[2];
    xg0_buf[0] = (float*)p;  p += (size_t)C * 196608;
    xg0_buf[1] = (float*)p;  p += (size_t)C * 196608;
    float* xg1_buf = (float*)p; p += (size_t)C * 196608;
    f16* h1_buf = (f16*)p;   p += (size_t)C * 32768;
    f16* h2_buf[2];
    h2_buf[0] = (f16*)p;     p += (size_t)C * 32768;
    h2_buf[1] = (f16*)p;

    cvt_weights<<<1280, 256, 0, stream>>>(Whh0, Whh1, Wih1, W1, wcvt);
    hipMemsetAsync(state0, 0, 2 * 65536, stream);
    xg0_stand<<<C, 512, 0, stream>>>(x, Wih0, bih0, xg0_buf[0], 0, C);

    for (int i = 0; i <= nC; ++i) {
        fused_step<<<128 + 2 * C, 512, 0, stream>>>(i, nC, C, lgC,
            x, Wih0, bih0, whh0_16, bhh0, whh1_16, bhh1, w1T, b1, W2, b2,
            xg0_buf[0], xg0_buf[1], xg1_buf, h1_buf, h2_buf[0], h2_buf[1],
            state0, state1, out);
        if (i < nC)
            xg1_kernel<<<dim3(C, 3), 256, 0, stream>>>(h1_buf, wih1T, bih1, xg1_buf, C);
    }
    reg_stand<<<C, 512, 0, stream>>>(h2_buf[(nC - 1) & 1], w1T, b1, W2, b2, out,
                                     (nC - 1) * C, C, lgC);
}